// Round 9
// baseline (176.488 us; speedup 1.0000x reference)
//
#include <hip/hip_runtime.h>

// out[b, I[e]] += inputs[b, J[e]] * W3[e] * velocity[J[e]]; out += bias
// R2: per-edge global atomics = 204.8MB atomic-path traffic (bound).
// R4: 8B scattered part writes: 47MB WRITE, 49us (partial-line XCD bounce).
// R6: counting sort w/ 84B runs: build fast; finesort starved -> 159us.
// R7-R10: fused gather 350-450us -> FP LDS atomics were the poison.
// R11: wave-exclusive += : gather 47.5us, total 161.8.
// R12: per-row bins + register acc, 782 fine buckets: total 148.9 (best).
// R13: quadrant-filter gather FALSIFIED (63.9us, part x4). Reverted.
// R14: velocity folded into in_T + prep/hist merge: 156.5 (within noise).
//     Cross-round accounting: total ~= gather + 104-114us REGARDLESS of
//     build structure -> non-gather component dominated by harness 256MB
//     re-poison fill (~47us/iter, interleaved in trace) + launch bubbles.
// R15: attack the controllable microseconds:
//     (a) k_scan launch + full-device bubble removed: LAST-BLOCK fusion in
//         prep_hist (threadfence + done-counter; sole last block scans 782
//         bins via coherent atomic reads, inits strided cursors). No spin.
//     (b) gather GCH 512->1024: half the syncs/cnt-resets, 2 rec/thread
//         phase A. 25KB LDS, still 4 blocks/CU (thread-limited).
//     Pipeline: memset(hist+done) + prep_hist_scan + partition + gather.

#define BATCH 64
#define QROWS 64              // rows per bucket == rows per gather block
#define PCHUNK 2048           // edges per hist/partition block
#define GCH 1024              // records per gather chunk (2/thread)
#define BCAP 32               // per-row bin capacity
#define BSTR 33               // padded bin stride (ull)
#define GSTR 16               // gcursor stride in ints (one per 64B line)

typedef unsigned long long ull;

// ---- K1: role-split + last-block scan fusion.
// Blocks [0,nb_n): transpose in [B,N] -> in_T [N,B] * velocity fold.
// Blocks [nb_n,nb_n+nb_e): 64-row histogram of I.
// Last block to finish: exclusive scan of NC bins -> coarse_base, gcursor. ----
__global__ void __launch_bounds__(256) k_prep_hist(
        const float* __restrict__ in, const float* __restrict__ velocity,
        float* __restrict__ in_T,
        const int* __restrict__ I, int* __restrict__ coarse_hist,
        int* __restrict__ done, int* __restrict__ coarse_base,
        int* __restrict__ gcursor,
        int NC, int N, int E, int nb_n, int ntotal) {
    __shared__ float tile[64 * 65];            // hist role aliases as int[]
    __shared__ int ps[256];
    __shared__ int amlast;
    const int t = threadIdx.x;

    if ((int)blockIdx.x < nb_n) {
        const int n0 = blockIdx.x * 64;
        const int x  = t & 63;
        const int r  = t >> 6;
        for (int b = r; b < BATCH; b += 4) {
            float v = 0.f;
            if (n0 + x < N) v = in[(size_t)b * N + n0 + x];
            tile[x * 65 + b] = v;
        }
        __syncthreads();
        for (int xr = r; xr < 64; xr += 4) {
            if (n0 + xr < N) {
                const float vel = velocity[n0 + xr];   // wave-uniform broadcast
                in_T[(size_t)(n0 + xr) * BATCH + x] = tile[xr * 65 + x] * vel;
            }
        }
    } else {
        int* h = (int*)tile;
        for (int c = t; c < NC; c += 256) h[c] = 0;
        __syncthreads();
        const int e0 = ((int)blockIdx.x - nb_n) * PCHUNK;
        int e1 = e0 + PCHUNK; if (e1 > E) e1 = E;
        for (int e = e0 + t; e < e1; e += 256) atomicAdd(&h[I[e] >> 6], 1);
        __syncthreads();
        for (int c = t; c < NC; c += 256) if (h[c]) atomicAdd(&coarse_hist[c], h[c]);
    }

    // ---- last-block scan (no spinning: only the unique last block works) ----
    __syncthreads();
    if (t == 0) {
        __threadfence();
        amlast = (atomicAdd(done, 1) == ntotal - 1) ? 1 : 0;
    }
    __syncthreads();
    if (amlast) {
        // thread t owns bins [4t, 4t+4); NC <= 1024
        int loc[4];
        int s = 0;
        #pragma unroll
        for (int k = 0; k < 4; ++k) {
            const int c = 4 * t + k;
            int v = 0;
            if (c < NC) v = atomicAdd(&coarse_hist[c], 0);  // coherent read (G16)
            loc[k] = s; s += v;
        }
        ps[t] = s;
        __syncthreads();
        for (int off = 1; off < 256; off <<= 1) {
            const int u = (t >= off) ? ps[t - off] : 0;
            __syncthreads();
            ps[t] += u;
            __syncthreads();
        }
        const int excl = ps[t] - s;
        #pragma unroll
        for (int k = 0; k < 4; ++k) {
            const int c = 4 * t + k;
            if (c < NC) {
                coarse_base[c]    = excl + loc[k];
                gcursor[c * GSTR] = excl + loc[k];
            }
        }
        if (t == 255) coarse_base[NC] = ps[255];   // = E
    }
}

// ---- K2: partition into 64-row buckets, single-pass register stash ----
// record u64: hi32 = bits(W3[e]), lo32 = (i & 63) << 16 | j
__global__ void __launch_bounds__(512) k_partition(
        const int* __restrict__ I, const int* __restrict__ J,
        const float* __restrict__ W3,
        int* __restrict__ gcursor, ull* __restrict__ part, int E, int NC) {
    __shared__ int hist[1024];
    __shared__ int base[1024];
    const int t = threadIdx.x;
    for (int c = t; c < NC; c += 512) hist[c] = 0;
    __syncthreads();
    const int e0 = blockIdx.x * PCHUNK;
    int e1 = e0 + PCHUNK; if (e1 > E) e1 = E;

    ull  rec[4];
    int  cb[4];
    int  rk[4];
    bool ok[4];
    #pragma unroll
    for (int u = 0; u < 4; ++u) {
        const int e = e0 + u * 512 + t;
        ok[u] = (e < e1);
        cb[u] = 0; rk[u] = 0; rec[u] = 0ull;
        if (ok[u]) {
            const int i = I[e];
            const int j = J[e];
            cb[u] = i >> 6;
            rk[u] = atomicAdd(&hist[cb[u]], 1);     // count IS the rank
            rec[u] = ((ull)__float_as_uint(W3[e]) << 32)
                   | ((ull)((unsigned)(i & 63) << 16) | (unsigned)j);
        }
    }
    __syncthreads();
    for (int c = t; c < NC; c += 512) {
        const int cnt = hist[c];
        base[c] = cnt ? atomicAdd(&gcursor[c * GSTR], cnt) : 0;
    }
    __syncthreads();
    #pragma unroll
    for (int u = 0; u < 4; ++u)
        if (ok[u]) part[(size_t)base[cb[u]] + rk[u]] = rec[u];
}

// ---- K3: gather. Block = one 64-row bucket. Per 1024-record chunk: ----
// Phase A: bin records by row (int cursor, CAP=32 + overflow list).
// Phase B: wave w drains rows [w*8,w*8+8) via uniform ds_read broadcast
// into register acc[8]. Tile aliased over bins; written once at end.
__global__ void __launch_bounds__(512) k_gather(
        const float* __restrict__ in_T, const ull* __restrict__ part,
        const int* __restrict__ coarse_base, const float* __restrict__ bias,
        float* __restrict__ out, int N) {
    __shared__ ull smem[64 * BSTR + GCH];       // bins[64][33] | ovf[1024]
    __shared__ int cnt[64];
    __shared__ int ocnt;
    ull* const bins = smem;
    ull* const ovf  = smem + 64 * BSTR;
    float* const tile = (float*)smem;           // 64x65 f32 = 2080 ull < 3136

    const int t    = threadIdx.x;
    const int lane = t & 63;
    const int w    = t >> 6;                    // wave 0..7 = row-octant owner
    const int c    = blockIdx.x;                // bucket == 64-row stripe

    const int beg = coarse_base[c];
    const int end = coarse_base[c + 1];

    float acc[8];
    #pragma unroll
    for (int r = 0; r < 8; ++r) acc[r] = 0.f;

    for (int cb = beg; cb < end; cb += GCH) {
        __syncthreads();                        // prev phase B done
        if (t < 64) cnt[t] = 0;
        if (t == 0) ocnt = 0;
        __syncthreads();

        // ---- phase A: place my 2 records into row bins (int atomics) ----
        #pragma unroll
        for (int u = 0; u < 2; ++u) {
            const int e = cb + u * 512 + t;
            if (e < end) {
                const ull rec = part[e];                      // coalesced
                const int li = (int)(((unsigned)rec >> 16) & 63u);
                const int r = atomicAdd(&cnt[li], 1);         // native int ds add
                if (r < BCAP) bins[li * BSTR + r] = rec;
                else          ovf[atomicAdd(&ocnt, 1)] = rec; // structurally safe
            }
        }
        __syncthreads();

        // ---- phase B: wave w drains its 8 rows; register accumulate ----
        #pragma unroll
        for (int r8 = 0; r8 < 8; ++r8) {
            const int row = w * 8 + r8;
            int n = cnt[row]; if (n > BCAP) n = BCAP;
            const ull* bp = &bins[row * BSTR];
            float a = acc[r8];
            int k = 0;
            for (; k + 4 <= n; k += 4) {
                const ull r0 = bp[k], r1 = bp[k + 1], r2 = bp[k + 2], r3 = bp[k + 3];
                const float v0 = in_T[(int)((unsigned)r0 & 0xffffu) * BATCH + lane];
                const float v1 = in_T[(int)((unsigned)r1 & 0xffffu) * BATCH + lane];
                const float v2 = in_T[(int)((unsigned)r2 & 0xffffu) * BATCH + lane];
                const float v3 = in_T[(int)((unsigned)r3 & 0xffffu) * BATCH + lane];
                a += v0 * __uint_as_float((unsigned)(r0 >> 32));
                a += v1 * __uint_as_float((unsigned)(r1 >> 32));
                a += v2 * __uint_as_float((unsigned)(r2 >> 32));
                a += v3 * __uint_as_float((unsigned)(r3 >> 32));
            }
            for (; k < n; ++k) {
                const ull rr = bp[k];
                a += in_T[(int)((unsigned)rr & 0xffffu) * BATCH + lane]
                   * __uint_as_float((unsigned)(rr >> 32));
            }
            acc[r8] = a;
        }

        // ---- overflow (rare; only for heavily skewed rows) ----
        const int oc = ocnt;
        if (oc > 0) {
            #pragma unroll
            for (int r8 = 0; r8 < 8; ++r8) {
                const int row = w * 8 + r8;
                float a = acc[r8];
                for (int k = 0; k < oc; ++k) {
                    const ull rr = ovf[k];
                    if ((int)(((unsigned)rr >> 16) & 63u) == row)
                        a += in_T[(int)((unsigned)rr & 0xffffu) * BATCH + lane]
                           * __uint_as_float((unsigned)(rr >> 32));
                }
                acc[r8] = a;
            }
        }
    }

    __syncthreads();                            // all bin reads complete
    #pragma unroll
    for (int r8 = 0; r8 < 8; ++r8)
        tile[(w * 8 + r8) * 65 + lane] = acc[r8];
    __syncthreads();

    // epilogue: rows [n0, n0+64) -> out[b*N+n] + bias, coalesced per wave
    const int n0  = c * QROWS;
    const int row = t & 63;
    const int bq  = t >> 6;
    const int n = n0 + row;
    if (n < N) {
        const float bv = bias[n];
        for (int b = bq; b < BATCH; b += 8)
            out[(size_t)b * N + n] = tile[row * 65 + b] + bv;
    }
}

// ---- fallback path (ws too small or N doesn't fit u16): direct atomics ----
__global__ void k_edge_scatter_direct(const float* __restrict__ in,
                                      const float* __restrict__ W3,
                                      const float* __restrict__ velocity,
                                      const int* __restrict__ I,
                                      const int* __restrict__ J,
                                      float* __restrict__ out, int N, int E) {
    const int lane = threadIdx.x & 63;
    const long wave   = (long)blockIdx.x * (blockDim.x >> 6) + (threadIdx.x >> 6);
    const long nwaves = (long)gridDim.x * (blockDim.x >> 6);
    for (long base = wave * 64; base < E; base += nwaves * 64) {
        const long e = base + lane;
        int iv = 0, jv = 0; float wvv = 0.f;
        if (e < E) { iv = I[e]; jv = J[e]; wvv = W3[e] * velocity[jv]; }
        const int cnt = (int)((E - base) < 64 ? (E - base) : 64);
        for (int k = 0; k < cnt; ++k) {
            const int   ii = __shfl(iv, k);
            const int   jj = __shfl(jv, k);
            const float wvx = __shfl(wvv, k);
            const float val = in[(size_t)lane * N + jj] * wvx;
            atomicAdd(&out[(size_t)lane * N + ii], val);
        }
    }
}

__global__ void k_add_bias(const float* __restrict__ bias, float* __restrict__ out, int N, int total) {
    int idx = blockIdx.x * blockDim.x + threadIdx.x;
    if (idx < total) out[idx] += bias[idx % N];
}

extern "C" void kernel_launch(void* const* d_in, const int* in_sizes, int n_in,
                              void* d_out, int out_size, void* d_ws, size_t ws_size,
                              hipStream_t stream) {
    const float* inputs   = (const float*)d_in[0];
    const float* W3       = (const float*)d_in[1];
    const float* bias     = (const float*)d_in[2];
    const float* velocity = (const float*)d_in[3];
    const int*   I        = (const int*)d_in[4];
    const int*   J        = (const int*)d_in[5];
    const int E = in_sizes[1];
    const int N = in_sizes[3];
    float* out = (float*)d_out;

    const size_t mat_elems = (size_t)N * BATCH;
    const int NC   = (N + QROWS - 1) / QROWS;       // 64-row buckets
    const int nb_n = (N + 63) / 64;
    const int nb_e = (E + PCHUNK - 1) / PCHUNK;
    const int ntot = nb_n + nb_e;

    // ws: in_T | part | coarse_hist(NC) | done(1) | coarse_base(NC+1) | gcursor
    const size_t need = mat_elems * sizeof(float)
                      + (size_t)E * sizeof(ull)
                      + (size_t)(NC + 1 + (NC + 1) + NC * GSTR) * sizeof(int);

    if (ws_size >= need && N <= 65535 && NC <= 1024) {
        float* in_T        = (float*)d_ws;
        ull*   part        = (ull*)(in_T + mat_elems);
        int*   coarse_hist = (int*)(part + E);
        int*   done        = coarse_hist + NC;
        int*   coarse_base = done + 1;
        int*   gcursor     = coarse_base + NC + 1;

        hipMemsetAsync(coarse_hist, 0, (size_t)(NC + 1) * sizeof(int), stream);
        k_prep_hist<<<ntot, 256,  0, stream>>>(inputs, velocity, in_T, I,
                                               coarse_hist, done, coarse_base,
                                               gcursor, NC, N, E, nb_n, ntot);
        k_partition<<<nb_e, 512,  0, stream>>>(I, J, W3, gcursor, part, E, NC);
        k_gather   <<<NC,   512,  0, stream>>>(in_T, part, coarse_base, bias, out, N);
    } else {
        hipMemsetAsync(out, 0, (size_t)out_size * sizeof(float), stream);
        const int waves_needed   = (E + 63) / 64;
        const int scatter_blocks = (waves_needed + 3) / 4;
        k_edge_scatter_direct<<<scatter_blocks, 256, 0, stream>>>(inputs, W3, velocity, I, J, out, N, E);
        k_add_bias<<<(out_size + 255) / 256, 256, 0, stream>>>(bias, out, N, out_size);
    }
}

// Round 11
// 152.708 us; speedup vs baseline: 1.1557x; 1.1557x over previous
//
#include <hip/hip_runtime.h>

// out[b, I[e]] += inputs[b, J[e]] * W3[e] * velocity[J[e]]; out += bias
// R2: per-edge global atomics = 204.8MB atomic-path traffic (bound).
// R4: 8B scattered part writes: 47MB WRITE, 49us (partial-line XCD bounce).
// R6: counting sort w/ 84B runs: build fast; finesort starved -> 159us.
// R7-R10: fused gather 350-450us -> FP LDS atomics were the poison.
// R11: wave-exclusive += : gather 47.5us, total 161.8.
// R12: per-row bins + register acc, 782 fine buckets: total 148.9 (BEST).
// R13: quadrant-filter gather FALSIFIED (63.9us, part x4). Reverted.
// R14: velocity fold + prep/hist merge: 156.5 (delta within +-8us noise;
//     merge suspect for a few us: mixed-role blocks -> tail effects).
// R15: last-block scan fusion REGRESSED (176.5): 1220 device-scope fences
//     cost more than the saved launch; confounded with GCH 512->1024.
// R16: DE-CONFOUND. Exact R12 structure (5 dispatches, GCH=512, separate
//     scan) + ONE delta: velocity folded into in_T at prep -> partition is
//     a pure 3-stream read. (R17: resubmit unchanged — R16 bench was an
//     infra failure: "container failed twice", no kernel signal.)

#define BATCH 64
#define QROWS 64              // rows per bucket == rows per gather block
#define PCHUNK 2048           // edges per hist/partition block
#define GCH 512               // records per gather chunk (= block threads)
#define BCAP 32               // per-row bin capacity
#define BSTR 33               // padded bin stride (ull)
#define GSTR 16               // gcursor stride in ints (one per 64B line)

typedef unsigned long long ull;

// ---- K1: transpose inputs [B,N] -> in_T [N,B] with velocity fold; ----
// ---- zero coarse histogram. ----
__global__ void k_prep(const float* __restrict__ in, const float* __restrict__ velocity,
                       float* __restrict__ in_T, int* __restrict__ coarse_hist,
                       int NC, int N) {
    const int gid = blockIdx.x * 256 + threadIdx.x;
    if (gid < NC) coarse_hist[gid] = 0;

    __shared__ float tile[64 * 65];
    const int n0 = blockIdx.x * 64;
    const int t  = threadIdx.x;
    const int x  = t & 63;
    const int r  = t >> 6;
    for (int b = r; b < BATCH; b += 4) {
        float v = 0.f;
        if (n0 + x < N) v = in[(size_t)b * N + n0 + x];
        tile[x * 65 + b] = v;
    }
    __syncthreads();
    for (int xr = r; xr < 64; xr += 4) {
        if (n0 + xr < N) {
            const float vel = velocity[n0 + xr];   // wave-uniform broadcast
            in_T[(size_t)(n0 + xr) * BATCH + x] = tile[xr * 65 + x] * vel;
        }
    }
}

// ---- K2: 64-row-bucket histogram (LDS-aggregated, up to 1024 bins) ----
__global__ void __launch_bounds__(512) k_hist(const int* __restrict__ I,
                                              int* __restrict__ coarse_hist,
                                              int E, int NC) {
    __shared__ int h[1024];
    const int t = threadIdx.x;
    for (int c = t; c < NC; c += 512) h[c] = 0;
    __syncthreads();
    const int e0 = blockIdx.x * PCHUNK;
    int e1 = e0 + PCHUNK; if (e1 > E) e1 = E;
    for (int e = e0 + t; e < e1; e += 512) atomicAdd(&h[I[e] >> 6], 1);
    __syncthreads();
    for (int c = t; c < NC; c += 512) if (h[c]) atomicAdd(&coarse_hist[c], h[c]);
}

// ---- K3: exclusive scan of NC (<=1024) counts; init strided cursors ----
__global__ void __launch_bounds__(1024) k_scan(const int* __restrict__ coarse_hist,
                                               int* __restrict__ coarse_base,
                                               int* __restrict__ gcursor, int NC) {
    __shared__ int sh[1024];
    const int t = threadIdx.x;
    const int v = (t < NC) ? coarse_hist[t] : 0;
    sh[t] = v;
    __syncthreads();
    for (int off = 1; off < 1024; off <<= 1) {
        const int u = (t >= off) ? sh[t - off] : 0;
        __syncthreads();
        sh[t] += u;
        __syncthreads();
    }
    if (t < NC) { coarse_base[t] = sh[t] - v; gcursor[t * GSTR] = sh[t] - v; }
    if (t == NC - 1) coarse_base[NC] = sh[t];   // = E
}

// ---- K4: partition into 64-row buckets, single-pass register stash ----
// record u64: hi32 = bits(W3[e]), lo32 = (i & 63) << 16 | j
// Pure stream: velocity already folded into in_T at prep.
__global__ void __launch_bounds__(512) k_partition(
        const int* __restrict__ I, const int* __restrict__ J,
        const float* __restrict__ W3,
        int* __restrict__ gcursor, ull* __restrict__ part, int E, int NC) {
    __shared__ int hist[1024];
    __shared__ int base[1024];
    const int t = threadIdx.x;
    for (int c = t; c < NC; c += 512) hist[c] = 0;
    __syncthreads();
    const int e0 = blockIdx.x * PCHUNK;
    int e1 = e0 + PCHUNK; if (e1 > E) e1 = E;

    ull  rec[4];
    int  cb[4];
    int  rk[4];
    bool ok[4];
    #pragma unroll
    for (int u = 0; u < 4; ++u) {
        const int e = e0 + u * 512 + t;
        ok[u] = (e < e1);
        cb[u] = 0; rk[u] = 0; rec[u] = 0ull;
        if (ok[u]) {
            const int i = I[e];
            const int j = J[e];
            cb[u] = i >> 6;
            rk[u] = atomicAdd(&hist[cb[u]], 1);     // count IS the rank
            rec[u] = ((ull)__float_as_uint(W3[e]) << 32)
                   | ((ull)((unsigned)(i & 63) << 16) | (unsigned)j);
        }
    }
    __syncthreads();
    for (int c = t; c < NC; c += 512) {
        const int cnt = hist[c];
        base[c] = cnt ? atomicAdd(&gcursor[c * GSTR], cnt) : 0;
    }
    __syncthreads();
    #pragma unroll
    for (int u = 0; u < 4; ++u)
        if (ok[u]) part[(size_t)base[cb[u]] + rk[u]] = rec[u];
}

// ---- K5: gather (R12-exact). Block = one 64-row bucket. Per 512-record
// chunk: phase A bins by row (int cursor, CAP=32 + overflow list); phase B:
// wave w drains rows [w*8,w*8+8) via uniform ds_read broadcast into register
// acc[8]. Tile aliased over bins; written once at end. ----
__global__ void __launch_bounds__(512) k_gather(
        const float* __restrict__ in_T, const ull* __restrict__ part,
        const int* __restrict__ coarse_base, const float* __restrict__ bias,
        float* __restrict__ out, int N) {
    __shared__ ull smem[64 * BSTR + GCH];       // bins[64][33] | ovf[512]
    __shared__ int cnt[64];
    __shared__ int ocnt;
    ull* const bins = smem;
    ull* const ovf  = smem + 64 * BSTR;
    float* const tile = (float*)smem;           // 64x65 f32 = 2080 ull < 2624

    const int t    = threadIdx.x;
    const int lane = t & 63;
    const int w    = t >> 6;                    // wave 0..7 = row-octant owner
    const int c    = blockIdx.x;                // bucket == 64-row stripe

    const int beg = coarse_base[c];
    const int end = coarse_base[c + 1];

    float acc[8];
    #pragma unroll
    for (int r = 0; r < 8; ++r) acc[r] = 0.f;

    for (int cb = beg; cb < end; cb += GCH) {
        __syncthreads();                        // prev phase B done
        if (t < 64) cnt[t] = 0;
        if (t == 0) ocnt = 0;
        __syncthreads();

        // ---- phase A: place my record into its row bin (int atomics) ----
        const int e = cb + t;
        if (e < end) {
            const ull rec = part[e];                      // coalesced
            const int li = (int)(((unsigned)rec >> 16) & 63u);
            const int r = atomicAdd(&cnt[li], 1);         // native int ds add
            if (r < BCAP) bins[li * BSTR + r] = rec;
            else          ovf[atomicAdd(&ocnt, 1)] = rec; // structurally safe
        }
        __syncthreads();

        // ---- phase B: wave w drains its 8 rows; register accumulate ----
        #pragma unroll
        for (int r8 = 0; r8 < 8; ++r8) {
            const int row = w * 8 + r8;
            int n = cnt[row]; if (n > BCAP) n = BCAP;
            const ull* bp = &bins[row * BSTR];
            float a = acc[r8];
            int k = 0;
            for (; k + 4 <= n; k += 4) {
                const ull r0 = bp[k], r1 = bp[k + 1], r2 = bp[k + 2], r3 = bp[k + 3];
                const float v0 = in_T[(int)((unsigned)r0 & 0xffffu) * BATCH + lane];
                const float v1 = in_T[(int)((unsigned)r1 & 0xffffu) * BATCH + lane];
                const float v2 = in_T[(int)((unsigned)r2 & 0xffffu) * BATCH + lane];
                const float v3 = in_T[(int)((unsigned)r3 & 0xffffu) * BATCH + lane];
                a += v0 * __uint_as_float((unsigned)(r0 >> 32));
                a += v1 * __uint_as_float((unsigned)(r1 >> 32));
                a += v2 * __uint_as_float((unsigned)(r2 >> 32));
                a += v3 * __uint_as_float((unsigned)(r3 >> 32));
            }
            for (; k < n; ++k) {
                const ull rr = bp[k];
                a += in_T[(int)((unsigned)rr & 0xffffu) * BATCH + lane]
                   * __uint_as_float((unsigned)(rr >> 32));
            }
            acc[r8] = a;
        }

        // ---- overflow (rare; only for heavily skewed rows) ----
        const int oc = ocnt;
        if (oc > 0) {
            #pragma unroll
            for (int r8 = 0; r8 < 8; ++r8) {
                const int row = w * 8 + r8;
                float a = acc[r8];
                for (int k = 0; k < oc; ++k) {
                    const ull rr = ovf[k];
                    if ((int)(((unsigned)rr >> 16) & 63u) == row)
                        a += in_T[(int)((unsigned)rr & 0xffffu) * BATCH + lane]
                           * __uint_as_float((unsigned)(rr >> 32));
                }
                acc[r8] = a;
            }
        }
    }

    __syncthreads();                            // all bin reads complete
    #pragma unroll
    for (int r8 = 0; r8 < 8; ++r8)
        tile[(w * 8 + r8) * 65 + lane] = acc[r8];
    __syncthreads();

    // epilogue: rows [n0, n0+64) -> out[b*N+n] + bias, coalesced per wave
    const int n0  = c * QROWS;
    const int row = t & 63;
    const int bq  = t >> 6;
    const int n = n0 + row;
    if (n < N) {
        const float bv = bias[n];
        for (int b = bq; b < BATCH; b += 8)
            out[(size_t)b * N + n] = tile[row * 65 + b] + bv;
    }
}

// ---- fallback path (ws too small or N doesn't fit u16): direct atomics ----
__global__ void k_edge_scatter_direct(const float* __restrict__ in,
                                      const float* __restrict__ W3,
                                      const float* __restrict__ velocity,
                                      const int* __restrict__ I,
                                      const int* __restrict__ J,
                                      float* __restrict__ out, int N, int E) {
    const int lane = threadIdx.x & 63;
    const long wave   = (long)blockIdx.x * (blockDim.x >> 6) + (threadIdx.x >> 6);
    const long nwaves = (long)gridDim.x * (blockDim.x >> 6);
    for (long base = wave * 64; base < E; base += nwaves * 64) {
        const long e = base + lane;
        int iv = 0, jv = 0; float wvv = 0.f;
        if (e < E) { iv = I[e]; jv = J[e]; wvv = W3[e] * velocity[jv]; }
        const int cnt = (int)((E - base) < 64 ? (E - base) : 64);
        for (int k = 0; k < cnt; ++k) {
            const int   ii = __shfl(iv, k);
            const int   jj = __shfl(jv, k);
            const float wvx = __shfl(wvv, k);
            const float val = in[(size_t)lane * N + jj] * wvx;
            atomicAdd(&out[(size_t)lane * N + ii], val);
        }
    }
}

__global__ void k_add_bias(const float* __restrict__ bias, float* __restrict__ out, int N, int total) {
    int idx = blockIdx.x * blockDim.x + threadIdx.x;
    if (idx < total) out[idx] += bias[idx % N];
}

extern "C" void kernel_launch(void* const* d_in, const int* in_sizes, int n_in,
                              void* d_out, int out_size, void* d_ws, size_t ws_size,
                              hipStream_t stream) {
    const float* inputs   = (const float*)d_in[0];
    const float* W3       = (const float*)d_in[1];
    const float* bias     = (const float*)d_in[2];
    const float* velocity = (const float*)d_in[3];
    const int*   I        = (const int*)d_in[4];
    const int*   J        = (const int*)d_in[5];
    const int E = in_sizes[1];
    const int N = in_sizes[3];
    float* out = (float*)d_out;

    const size_t mat_elems = (size_t)N * BATCH;
    const int NC   = (N + QROWS - 1) / QROWS;       // 64-row buckets
    const int nb_n = (N + 63) / 64;
    const int nb_e = (E + PCHUNK - 1) / PCHUNK;

    // ws: in_T | part | coarse_hist | coarse_base | gcursor(strided)
    const size_t need = mat_elems * sizeof(float)
                      + (size_t)E * sizeof(ull)
                      + (size_t)(NC + (NC + 1) + NC * GSTR) * sizeof(int);

    if (ws_size >= need && N <= 65535 && NC <= 1024) {
        float* in_T        = (float*)d_ws;
        ull*   part        = (ull*)(in_T + mat_elems);
        int*   coarse_hist = (int*)(part + E);
        int*   coarse_base = coarse_hist + NC;
        int*   gcursor     = coarse_base + NC + 1;

        k_prep     <<<nb_n, 256,  0, stream>>>(inputs, velocity, in_T, coarse_hist, NC, N);
        k_hist     <<<nb_e, 512,  0, stream>>>(I, coarse_hist, E, NC);
        k_scan     <<<1,    1024, 0, stream>>>(coarse_hist, coarse_base, gcursor, NC);
        k_partition<<<nb_e, 512,  0, stream>>>(I, J, W3, gcursor, part, E, NC);
        k_gather   <<<NC,   512,  0, stream>>>(in_T, part, coarse_base, bias, out, N);
    } else {
        hipMemsetAsync(out, 0, (size_t)out_size * sizeof(float), stream);
        const int waves_needed   = (E + 63) / 64;
        const int scatter_blocks = (waves_needed + 3) / 4;
        k_edge_scatter_direct<<<scatter_blocks, 256, 0, stream>>>(inputs, W3, velocity, I, J, out, N, E);
        k_add_bias<<<(out_size + 255) / 256, 256, 0, stream>>>(bias, out, N, out_size);
    }
}